// Round 1
// baseline (10561.925 us; speedup 1.0000x reference)
//
#include <hip/hip_runtime.h>
#include <hip/hip_bf16.h>

// Problem constants
#define BB 8
#define CC 128
#define TT 8
#define HH 56
#define WW2 56
#define NWIN_T 4   // T/2
#define NWIN_H 8   // H/7
#define NWIN_W 8   // W/7
#define NTOK 98    // 2*7*7
#define WIN_PER_B 256
#define BNW 2048
#define PSPAT 25088          // T*H*W
#define TOK_TOTAL 200704     // B*PSPAT
#define ACT_ELEMS 25690112   // TOK_TOTAL * C

// ---------------- transpose in: (B,C,P) -> (B,P,C) ----------------
__global__ __launch_bounds__(256) void k_transpose_in(const float* __restrict__ in,
                                                      float* __restrict__ xbuf) {
    __shared__ float tile[32][33];
    int p0 = blockIdx.x * 32, c0 = blockIdx.y * 32, b = blockIdx.z;
    int pi = threadIdx.x, ci = threadIdx.y;  // 32 x 8
    const float* src = in + ((size_t)b * CC + c0) * PSPAT + p0;
    for (int r = 0; r < 32; r += 8)
        tile[ci + r][pi] = src[(size_t)(ci + r) * PSPAT + pi];
    __syncthreads();
    float* dst = xbuf + ((size_t)b * PSPAT + p0) * CC + c0;
    for (int r = 0; r < 32; r += 8)
        dst[(size_t)(ci + r) * CC + pi] = tile[pi][ci + r];
}

// ---------------- transpose out: (B,P,C) -> (B,C,P) ----------------
__global__ __launch_bounds__(256) void k_transpose_out(const float* __restrict__ xbuf,
                                                       float* __restrict__ out) {
    __shared__ float tile[32][33];
    int p0 = blockIdx.x * 32, c0 = blockIdx.y * 32, b = blockIdx.z;
    int pi = threadIdx.x, ci = threadIdx.y;
    const float* src = xbuf + ((size_t)b * PSPAT + p0) * CC + c0;
    for (int r = 0; r < 32; r += 8)
        tile[ci + r][pi] = src[(size_t)(ci + r) * CC + pi];
    __syncthreads();
    float* dst = out + ((size_t)b * CC + c0) * PSPAT + p0;
    for (int r = 0; r < 32; r += 8)
        dst[(size_t)(ci + r) * PSPAT + pi] = tile[pi][ci + r];
}

// ---------------- layernorm (+ optional roll + window partition gather) ----------
// mode 0: y[t] = LN(x[t])                    (plain, token order)
// mode 1: y[win-token] = LN(x[mapped])       (partition, no shift)
// mode 2: y[win-token] = LN(x[mapped+shift]) (partition + roll)
__global__ __launch_bounds__(256) void k_ln(const float* __restrict__ x,
                                            float* __restrict__ y,
                                            const float* __restrict__ g,
                                            const float* __restrict__ bta,
                                            int mode) {
    int wt = blockIdx.x * 4 + (threadIdx.x >> 6);
    int lane = threadIdx.x & 63;
    size_t src;
    if (mode == 0) {
        src = (size_t)wt;
    } else {
        int w_idx = wt / NTOK, n = wt - w_idx * NTOK;
        int b = w_idx >> 8;
        int wrem = w_idx & 255;
        int tw = wrem >> 6, hw = (wrem >> 3) & 7, ww = wrem & 7;
        int it = n / 49, r = n - it * 49, ih = r / 7, iw = r - ih * 7;
        int t = tw * 2 + it, h = hw * 7 + ih, w = ww * 7 + iw;
        if (mode == 2) {
            t += 1; if (t >= TT) t -= TT;
            h += 3; if (h >= HH) h -= HH;
            w += 3; if (w >= WW2) w -= WW2;
        }
        src = (size_t)b * PSPAT + t * (HH * WW2) + h * WW2 + w;
    }
    float2 v = *(const float2*)(x + src * CC + lane * 2);
    float s = v.x + v.y, sq = v.x * v.x + v.y * v.y;
    for (int o = 32; o; o >>= 1) { s += __shfl_xor(s, o); sq += __shfl_xor(sq, o); }
    float mu = s * (1.f / 128.f);
    float var = sq * (1.f / 128.f) - mu * mu;
    float rs = rsqrtf(var + 1e-5f);
    float2 gg = *(const float2*)(g + lane * 2);
    float2 bb = *(const float2*)(bta + lane * 2);
    float2 o2;
    o2.x = (v.x - mu) * rs * gg.x + bb.x;
    o2.y = (v.y - mu) * rs * gg.y + bb.y;
    *(float2*)(y + (size_t)wt * CC + lane * 2) = o2;
}

// ---------------- attention: inline qkv per (window, head) ----------------
__global__ __launch_bounds__(128) void k_attn(const float* __restrict__ y,
                                              const float* __restrict__ qkvw,
                                              const float* __restrict__ qkvb,
                                              const float* __restrict__ rp,
                                              float* __restrict__ out,
                                              int shifted) {
    __shared__ float kl[NTOK * 33];
    __shared__ float vl[NTOK * 33];
    __shared__ float sc[NTOK * 99];
    __shared__ int mcoord[NTOK];
    int w_idx = blockIdx.x, head = blockIdx.y;
    int tid = threadIdx.x;
    int wrem = w_idx & 255;
    int tw = wrem >> 6, hw = (wrem >> 3) & 7, ww = wrem & 7;
    for (int m = tid; m < NTOK; m += 128) {
        int it = m / 49, r = m - it * 49, ih = r / 7, iw = r - ih * 7;
        int lab = 0;
        if (shifted) {
            int t = tw * 2 + it, h = hw * 7 + ih, w = ww * 7 + iw;
            int ct = (t < TT - 2) ? 0 : ((t < TT - 1) ? 1 : 2);
            int ch = (h < HH - 7) ? 0 : ((h < HH - 3) ? 1 : 2);
            int cw = (w < WW2 - 7) ? 0 : ((w < WW2 - 3) ? 1 : 2);
            lab = ct * 9 + ch * 3 + cw;
        }
        mcoord[m] = it | (ih << 4) | (iw << 8) | (lab << 12);
    }
    __syncthreads();
    int n = tid;
    float qa[32];
    if (n < NTOK) {
        float ka[32], va[32];
        const float* yr = y + ((size_t)w_idx * NTOK + n) * CC;
        const float* bq = qkvb + head * 32;
        for (int j = 0; j < 32; j++) { qa[j] = bq[j]; ka[j] = bq[128 + j]; va[j] = bq[256 + j]; }
        for (int k = 0; k < 128; k++) {
            float yv = yr[k];
            const float* wr = qkvw + k * 384 + head * 32;
            #pragma unroll
            for (int j = 0; j < 32; j++) {
                qa[j] = fmaf(yv, wr[j], qa[j]);
                ka[j] = fmaf(yv, wr[128 + j], ka[j]);
                va[j] = fmaf(yv, wr[256 + j], va[j]);
            }
        }
        for (int j = 0; j < 32; j++) { kl[n * 33 + j] = ka[j]; vl[n * 33 + j] = va[j]; }
    }
    __syncthreads();
    if (n < NTOK) {
        int cn = mcoord[n];
        int nt = cn & 15, nh = (cn >> 4) & 15, nw = (cn >> 8) & 15, nlab = cn >> 12;
        float mx = -1e30f;
        for (int m = 0; m < NTOK; m++) {
            float s = 0.f;
            #pragma unroll
            for (int j = 0; j < 32; j++) s = fmaf(qa[j], kl[m * 33 + j], s);
            s *= 0.17677669529663687f;
            int cm = mcoord[m];
            int dt = nt - (cm & 15) + 1;
            int dh = nh - ((cm >> 4) & 15) + 6;
            int dw = nw - ((cm >> 8) & 15) + 6;
            s += rp[(dt * 169 + dh * 13 + dw) * 4 + head];
            if (shifted && ((cm >> 12) != nlab)) s -= 100.f;
            sc[n * 99 + m] = s;
            mx = fmaxf(mx, s);
        }
        float sum = 0.f;
        for (int m = 0; m < NTOK; m++) {
            float e = __expf(sc[n * 99 + m] - mx);
            sum += e;
            sc[n * 99 + m] = e;
        }
        float inv = 1.f / sum;
        float o[32];
        for (int j = 0; j < 32; j++) o[j] = 0.f;
        for (int m = 0; m < NTOK; m++) {
            float p = sc[n * 99 + m];
            #pragma unroll
            for (int j = 0; j < 32; j++) o[j] = fmaf(p, vl[m * 33 + j], o[j]);
        }
        float* op = out + ((size_t)w_idx * NTOK + n) * CC + head * 32;
        for (int j = 0; j < 32; j++) op[j] = o[j] * inv;
    }
}

// ---------------- proj GEMM + window-reverse + roll-back scatter-add ----------
__global__ __launch_bounds__(256) void k_proj(const float* __restrict__ a,
                                              const float* __restrict__ wmat,
                                              const float* __restrict__ bias,
                                              float* __restrict__ xbuf,
                                              int shifted) {
    __shared__ float al[32 * 132];
    int row0 = blockIdx.x * 32;
    int tid = threadIdx.x;
    for (int idx = tid; idx < 32 * 128; idx += 256) {
        int t = idx >> 7, c = idx & 127;
        al[t * 132 + c] = a[(size_t)(row0 + t) * CC + c];
    }
    __syncthreads();
    int t = tid >> 3, colg = (tid & 7) * 16;
    float acc[16];
    for (int j = 0; j < 16; j++) acc[j] = bias[colg + j];
    for (int k = 0; k < 128; k++) {
        float av = al[t * 132 + k];
        const float* wr = wmat + k * 128 + colg;
        #pragma unroll
        for (int j = 0; j < 16; j++) acc[j] = fmaf(av, wr[j], acc[j]);
    }
    int wt = row0 + t;
    int w_idx = wt / NTOK, n = wt - w_idx * NTOK;
    int b = w_idx >> 8;
    int wrem = w_idx & 255;
    int tw = wrem >> 6, hw = (wrem >> 3) & 7, ww = wrem & 7;
    int it = n / 49, r = n - it * 49, ih = r / 7, iw = r - ih * 7;
    int tt = tw * 2 + it, hh = hw * 7 + ih, wp = ww * 7 + iw;
    if (shifted) {
        tt += 1; if (tt >= TT) tt -= TT;
        hh += 3; if (hh >= HH) hh -= HH;
        wp += 3; if (wp >= WW2) wp -= WW2;
    }
    float* xp = xbuf + ((size_t)b * PSPAT + tt * (HH * WW2) + hh * WW2 + wp) * CC + colg;
    for (int j = 0; j < 16; j++) xp[j] += acc[j];
}

// ---------------- fused MLP: gelu(h@fc1+b1)@fc2+b2, += xbuf ----------------
__global__ __launch_bounds__(256) void k_mlp(const float* __restrict__ h,
                                             const float* __restrict__ w1,
                                             const float* __restrict__ b1,
                                             const float* __restrict__ w2,
                                             const float* __restrict__ b2,
                                             float* __restrict__ xbuf) {
    __shared__ float hl[16 * 132];
    __shared__ float ul[16 * 516];
    int row0 = blockIdx.x * 16;
    int tid = threadIdx.x;
    for (int idx = tid; idx < 16 * 128; idx += 256) {
        int t = idx >> 7, c = idx & 127;
        hl[t * 132 + c] = h[(size_t)(row0 + t) * CC + c];
    }
    __syncthreads();
    {
        int t = tid >> 4, jl = tid & 15;  // outputs j = jl + 16*jj
        float acc[32];
        for (int jj = 0; jj < 32; jj++) acc[jj] = b1[jl + 16 * jj];
        for (int k = 0; k < 128; k++) {
            float hv = hl[t * 132 + k];
            const float* wr = w1 + k * 512 + jl;
            #pragma unroll
            for (int jj = 0; jj < 32; jj++) acc[jj] = fmaf(hv, wr[16 * jj], acc[jj]);
        }
        for (int jj = 0; jj < 32; jj++) {
            float xg = acc[jj];
            float gel = xg * 0.5f * (1.f + erff(xg * 0.7071067811865475f));
            ul[t * 516 + jl + 16 * jj] = gel;
        }
    }
    __syncthreads();
    {
        int t = tid >> 4, colg = (tid & 15) * 8;
        float acc[8];
        for (int j = 0; j < 8; j++) acc[j] = b2[colg + j];
        for (int k = 0; k < 512; k++) {
            float uv = ul[t * 516 + k];
            const float* wr = w2 + k * 128 + colg;
            #pragma unroll
            for (int j = 0; j < 8; j++) acc[j] = fmaf(uv, wr[j], acc[j]);
        }
        float* xp = xbuf + (size_t)(row0 + t) * CC + colg;
        for (int j = 0; j < 8; j++) xp[j] += acc[j];
    }
}

extern "C" void kernel_launch(void* const* d_in, const int* in_sizes, int n_in,
                              void* d_out, int out_size, void* d_ws, size_t ws_size,
                              hipStream_t stream) {
    const float* x_in   = (const float*)d_in[0];
    const float* ln1_g  = (const float*)d_in[1];
    const float* ln1_b  = (const float*)d_in[2];
    const float* qkv_w  = (const float*)d_in[3];
    const float* qkv_b  = (const float*)d_in[4];
    const float* rpb    = (const float*)d_in[5];
    const float* proj_w = (const float*)d_in[6];
    const float* proj_b = (const float*)d_in[7];
    const float* ln2_g  = (const float*)d_in[8];
    const float* ln2_b  = (const float*)d_in[9];
    const float* fc1_w  = (const float*)d_in[10];
    const float* fc1_b  = (const float*)d_in[11];
    const float* fc2_w  = (const float*)d_in[12];
    const float* fc2_b  = (const float*)d_in[13];
    float* out = (float*)d_out;

    float* xbuf = (float*)d_ws;
    float* ybuf = xbuf + ACT_ELEMS;
    float* abuf = ybuf + ACT_ELEMS;

    k_transpose_in<<<dim3(PSPAT / 32, 4, BB), dim3(32, 8), 0, stream>>>(x_in, xbuf);

    for (int layer = 0; layer < 2; layer++) {
        const float* l1g = ln1_g + layer * 128;
        const float* l1b = ln1_b + layer * 128;
        const float* qw  = qkv_w + (size_t)layer * 128 * 384;
        const float* qb  = qkv_b + layer * 384;
        const float* rp  = rpb   + (size_t)layer * 507 * 4;
        const float* pw  = proj_w + (size_t)layer * 128 * 128;
        const float* pb  = proj_b + layer * 128;
        const float* l2g = ln2_g + layer * 128;
        const float* l2b = ln2_b + layer * 128;
        const float* w1  = fc1_w + (size_t)layer * 128 * 512;
        const float* b1  = fc1_b + layer * 512;
        const float* w2  = fc2_w + (size_t)layer * 512 * 128;
        const float* b2  = fc2_b + layer * 128;
        int shifted = layer & 1;

        // LN1 + roll + window-partition gather
        k_ln<<<TOK_TOTAL / 4, 256, 0, stream>>>(xbuf, ybuf, l1g, l1b, shifted ? 2 : 1);
        // attention (inline qkv per window/head)
        k_attn<<<dim3(BNW, 4), 128, 0, stream>>>(ybuf, qw, qb, rp, abuf, shifted);
        // proj + window-reverse + roll-back scatter-add into residual
        k_proj<<<TOK_TOTAL / 32, 256, 0, stream>>>(abuf, pw, pb, xbuf, shifted);
        // LN2 (plain token order)
        k_ln<<<TOK_TOTAL / 4, 256, 0, stream>>>(xbuf, ybuf, l2g, l2b, 0);
        // fused MLP
        k_mlp<<<TOK_TOTAL / 16, 256, 0, stream>>>(ybuf, w1, b1, w2, b2, xbuf);
    }

    k_transpose_out<<<dim3(PSPAT / 32, 4, BB), dim3(32, 8), 0, stream>>>(xbuf, out);
}

// Round 2
// 1474.584 us; speedup vs baseline: 7.1626x; 7.1626x over previous
//
#include <hip/hip_runtime.h>
#include <hip/hip_bf16.h>

typedef __attribute__((ext_vector_type(8))) short sv8_t;   // 8 bf16 (4 VGPR)
typedef __attribute__((ext_vector_type(4))) float fv4_t;   // MFMA accumulator
typedef __attribute__((ext_vector_type(4))) float f4ld_t;  // global float4 load

#define BB 8
#define TT 8
#define HH 56
#define WW2 56
#define NTOK 98
#define BNW 2048
#define PSPAT 25088
#define TOK_TOTAL 200704
#define ACT_ELEMS 25690112

#define SWZB(row, cb) ((cb) ^ ((((unsigned)(row)) & 7u) << 4))

__device__ __forceinline__ unsigned short f2bf(float f) {
    union { float f; unsigned u; } x; x.f = f;
    unsigned r = x.u + 0x7fffu + ((x.u >> 16) & 1u);
    return (unsigned short)(r >> 16);
}
__device__ __forceinline__ sv8_t lds_ld8(const unsigned short* p, int byteoff) {
    return *(const sv8_t*)((const char*)p + byteoff);
}
__device__ __forceinline__ void lds_st8(unsigned short* p, int byteoff, sv8_t v) {
    *(sv8_t*)((char*)p + byteoff) = v;
}
__device__ __forceinline__ void lds_st1(unsigned short* p, int byteoff, unsigned short v) {
    *(unsigned short*)((char*)p + byteoff) = v;
}

// ---------------- transpose in: (B,C,P) -> (B,P,C) f32 ----------------
__global__ __launch_bounds__(256) void k_transpose_in(const float* __restrict__ in,
                                                      float* __restrict__ xbuf) {
    __shared__ float tile[32][33];
    int p0 = blockIdx.x * 32, c0 = blockIdx.y * 32, b = blockIdx.z;
    int pi = threadIdx.x, ci = threadIdx.y;
    const float* src = in + ((size_t)b * 128 + c0) * PSPAT + p0;
    for (int r = 0; r < 32; r += 8)
        tile[ci + r][pi] = src[(size_t)(ci + r) * PSPAT + pi];
    __syncthreads();
    float* dst = xbuf + ((size_t)b * PSPAT + p0) * 128 + c0;
    for (int r = 0; r < 32; r += 8)
        dst[(size_t)(ci + r) * 128 + pi] = tile[pi][ci + r];
}

// ---------------- transpose out: (B,P,C) -> (B,C,P) ----------------
__global__ __launch_bounds__(256) void k_transpose_out(const float* __restrict__ xbuf,
                                                       float* __restrict__ out) {
    __shared__ float tile[32][33];
    int p0 = blockIdx.x * 32, c0 = blockIdx.y * 32, b = blockIdx.z;
    int pi = threadIdx.x, ci = threadIdx.y;
    const float* src = xbuf + ((size_t)b * PSPAT + p0) * 128 + c0;
    for (int r = 0; r < 32; r += 8)
        tile[ci + r][pi] = src[(size_t)(ci + r) * 128 + pi];
    __syncthreads();
    float* dst = out + ((size_t)b * 128 + c0) * PSPAT + p0;
    for (int r = 0; r < 32; r += 8)
        dst[(size_t)(ci + r) * PSPAT + pi] = tile[pi][ci + r];
}

// ---------------- weight prep: in f32 [K][N] -> out bf16 [N][K] ----------------
__global__ __launch_bounds__(256) void k_prep_w(const float* __restrict__ in,
                                                unsigned short* __restrict__ out,
                                                int K, int N) {
    __shared__ float tile[32][33];
    int n0 = blockIdx.x * 32, k0 = blockIdx.y * 32;
    int x = threadIdx.x, y = threadIdx.y;
    for (int r = 0; r < 32; r += 8)
        tile[y + r][x] = in[(size_t)(k0 + y + r) * N + n0 + x];
    __syncthreads();
    for (int r = 0; r < 32; r += 8)
        out[(size_t)(n0 + y + r) * K + k0 + x] = f2bf(tile[x][y + r]);
}

// ---------------- bias prep: biasb[layer][head][112][112] ----------------
__global__ void k_prep_bias(const float* __restrict__ rpb, float* __restrict__ biasb) {
    int col = threadIdx.x;   // 0..111
    int row = blockIdx.x;    // 0..111
    int head = blockIdx.y;   // 0..3
    int layer = blockIdx.z;
    int tn = min(row, 97), tm = min(col, 97);
    int itn = tn / 49, rn = tn - itn * 49, ihn = rn / 7, iwn = rn - ihn * 7;
    int itm = tm / 49, rm = tm - itm * 49, ihm = rm / 7, iwm = rm - ihm * 7;
    int dt = itn - itm + 1, dh = ihn - ihm + 6, dw = iwn - iwm + 6;
    float v = rpb[((size_t)layer * 507 + dt * 169 + dh * 13 + dw) * 4 + head];
    biasb[(((size_t)layer * 4 + head) * 112 + row) * 112 + col] = v;
}

// ---------------- fused LN1 + gather + qkv GEMM ----------------
// out qkvbuf bf16 [200704][384], Q cols pre-scaled.
__global__ __launch_bounds__(256) void k_qkv(const float* __restrict__ xbuf,
                                             const float* __restrict__ g,
                                             const float* __restrict__ be,
                                             const unsigned short* __restrict__ wT,  // [384][128]
                                             const float* __restrict__ bias,         // [384]
                                             unsigned short* __restrict__ qkvbuf,
                                             int shifted) {
    __shared__ unsigned short xt[64 * 128];
    int tid = threadIdx.x;
    int row0 = blockIdx.x * 64;
    {
        int r = tid >> 2, q = tid & 3;
        int wt = row0 + r;
        int win = wt / 98, n = wt - win * 98;
        int b_ = win >> 8, wrem = win & 255;
        int tw = wrem >> 6, hw = (wrem >> 3) & 7, ww = wrem & 7;
        int it = n / 49, r2 = n - it * 49, ih = r2 / 7, iw = r2 - ih * 7;
        int t = tw * 2 + it, h = hw * 7 + ih, w = ww * 7 + iw;
        if (shifted) {
            t += 1; if (t >= TT) t -= TT;
            h += 3; if (h >= HH) h -= HH;
            w += 3; if (w >= WW2) w -= WW2;
        }
        const float* src = xbuf + ((size_t)b_ * PSPAT + t * (HH * WW2) + h * WW2 + w) * 128 + q * 32;
        float v[32];
        float s = 0.f, sq = 0.f;
        for (int i = 0; i < 8; i++) {
            f4ld_t f = *(const f4ld_t*)(src + i * 4);
            v[i * 4 + 0] = f.x; v[i * 4 + 1] = f.y; v[i * 4 + 2] = f.z; v[i * 4 + 3] = f.w;
            s += f.x + f.y + f.z + f.w;
            sq += f.x * f.x + f.y * f.y + f.z * f.z + f.w * f.w;
        }
        s += __shfl_xor(s, 1); sq += __shfl_xor(sq, 1);
        s += __shfl_xor(s, 2); sq += __shfl_xor(sq, 2);
        float mu = s * (1.f / 128.f);
        float var = sq * (1.f / 128.f) - mu * mu;
        float rs = rsqrtf(var + 1e-5f);
        for (int c0 = 0; c0 < 32; c0 += 8) {
            sv8_t o;
            #pragma unroll
            for (int i = 0; i < 8; i++) {
                int c = q * 32 + c0 + i;
                o[i] = (short)f2bf((v[c0 + i] - mu) * rs * g[c] + be[c]);
            }
            lds_st8(xt, r * 256 + SWZB(r, (q * 32 + c0) * 2), o);
        }
    }
    __syncthreads();
    int wv = tid >> 6, lane = tid & 63, l15 = lane & 15, lhi = lane >> 4;
    int nb = wv * 96;
    fv4_t acc[4][6];
    for (int m = 0; m < 4; m++) for (int j = 0; j < 6; j++) acc[m][j] = (fv4_t){0.f, 0.f, 0.f, 0.f};
    for (int kk = 0; kk < 4; kk++) {
        sv8_t a[4];
        #pragma unroll
        for (int m = 0; m < 4; m++) {
            int ar = 16 * m + l15;
            a[m] = lds_ld8(xt, ar * 256 + SWZB(ar, (kk * 32 + 8 * lhi) * 2));
        }
        #pragma unroll
        for (int j = 0; j < 6; j++) {
            sv8_t b = *(const sv8_t*)(wT + (size_t)(nb + 16 * j + l15) * 128 + kk * 32 + 8 * lhi);
            #pragma unroll
            for (int m = 0; m < 4; m++)
                acc[m][j] = __builtin_amdgcn_mfma_f32_16x16x32_bf16(a[m], b, acc[m][j], 0, 0, 0);
        }
    }
    const float scq = 0.17677669529663687f;
    for (int j = 0; j < 6; j++) {
        int col = nb + 16 * j + l15;
        float bb = bias[col];
        float sc_ = (col < 128) ? scq : 1.f;
        #pragma unroll
        for (int m = 0; m < 4; m++)
            #pragma unroll
            for (int r = 0; r < 4; r++) {
                int row = row0 + 16 * m + lhi * 4 + r;
                qkvbuf[(size_t)row * 384 + col] = f2bf((acc[m][j][r] + bb) * sc_);
            }
    }
}

// ---------------- attention core + proj, one block per window ----------------
__global__ __launch_bounds__(256) void k_attn_proj(const unsigned short* __restrict__ qkv,
                                                   const float* __restrict__ biasb,  // [4][112][112]
                                                   const unsigned short* __restrict__ pwT, // [128][128]
                                                   const float* __restrict__ pb,
                                                   float* __restrict__ xbuf,
                                                   int shifted) {
    __shared__ unsigned short pt[4 * 16 * 128];
    __shared__ unsigned short ot[112 * 128];
    __shared__ int lablut[112];
    int win = blockIdx.x;
    int tid = threadIdx.x;
    int wv = tid >> 6, lane = tid & 63;
    int head = wv;
    int l15 = lane & 15, lhi = lane >> 4;
    int wrem = win & 255;
    int tw = wrem >> 6, hw = (wrem >> 3) & 7, ww = wrem & 7;

    for (int m = tid; m < 112; m += 256) {
        int t0 = min(m, 97);
        int it = t0 / 49, r2 = t0 - it * 49, ih = r2 / 7, iw = r2 - ih * 7;
        int lab = 0;
        if (shifted) {
            int t = tw * 2 + it, h = hw * 7 + ih, w = ww * 7 + iw;
            int ct = (t < TT - 2) ? 0 : ((t < TT - 1) ? 1 : 2);
            int ch = (h < HH - 7) ? 0 : ((h < HH - 3) ? 1 : 2);
            int cw = (w < WW2 - 7) ? 0 : ((w < WW2 - 3) ? 1 : 2);
            lab = ct * 9 + ch * 3 + cw;
        }
        lablut[m] = lab;
    }
    {   // zero P pad cols 112..127 (per wave tile)
        unsigned short* myp = pt + wv * 16 * 128;
        for (int idx = lane; idx < 256; idx += 64) {
            int r = idx >> 4, c = 112 + (idx & 15);
            lds_st1(myp, r * 256 + SWZB(r, c * 2), 0);
        }
    }
    __syncthreads();

    size_t rowbase = (size_t)win * 98;
    sv8_t kf[7];
    #pragma unroll
    for (int j = 0; j < 7; j++) {
        int tok = min(16 * j + l15, 97);
        kf[j] = *(const sv8_t*)(qkv + (rowbase + tok) * 384 + 128 + head * 32 + 8 * lhi);
    }
    sv8_t vf[4][2];
    for (int kk = 0; kk < 4; kk++)
        for (int j = 0; j < 2; j++) {
            sv8_t t;
            #pragma unroll
            for (int i = 0; i < 8; i++) {
                int tok = min(kk * 32 + 8 * lhi + i, 97);
                t[i] = (short)qkv[(rowbase + tok) * 384 + 256 + head * 32 + 16 * j + l15];
            }
            vf[kk][j] = t;
        }

    unsigned short* myp = pt + wv * 16 * 128;
    const float* bslice = biasb + (size_t)head * 112 * 112;

    for (int ms = 0; ms < 7; ms++) {
        int qtok = min(16 * ms + l15, 97);
        sv8_t qa = *(const sv8_t*)(qkv + (rowbase + qtok) * 384 + head * 32 + 8 * lhi);
        fv4_t sc[7];
        #pragma unroll
        for (int j = 0; j < 7; j++) {
            fv4_t z = {0.f, 0.f, 0.f, 0.f};
            sc[j] = __builtin_amdgcn_mfma_f32_16x16x32_bf16(qa, kf[j], z, 0, 0, 0);
        }
        float mx[4] = {-1e30f, -1e30f, -1e30f, -1e30f};
        int rowt[4];
        #pragma unroll
        for (int r = 0; r < 4; r++) rowt[r] = 16 * ms + lhi * 4 + r;
        #pragma unroll
        for (int j = 0; j < 7; j++) {
            int col = 16 * j + l15;
            int labc = lablut[col];
            bool colpad = (col >= 98);
            #pragma unroll
            for (int r = 0; r < 4; r++) {
                float s = sc[j][r] + bslice[rowt[r] * 112 + col];
                if (shifted && labc != lablut[rowt[r]]) s -= 100.f;
                if (colpad) s = -1e30f;
                sc[j][r] = s;
                mx[r] = fmaxf(mx[r], s);
            }
        }
        #pragma unroll
        for (int o = 1; o < 16; o <<= 1)
            #pragma unroll
            for (int r = 0; r < 4; r++) mx[r] = fmaxf(mx[r], __shfl_xor(mx[r], o));
        float sm[4] = {0.f, 0.f, 0.f, 0.f};
        #pragma unroll
        for (int j = 0; j < 7; j++)
            #pragma unroll
            for (int r = 0; r < 4; r++) {
                float p = __expf(sc[j][r] - mx[r]);
                sc[j][r] = p;
                sm[r] += p;
            }
        #pragma unroll
        for (int o = 1; o < 16; o <<= 1)
            #pragma unroll
            for (int r = 0; r < 4; r++) sm[r] += __shfl_xor(sm[r], o);
        #pragma unroll
        for (int j = 0; j < 7; j++)
            #pragma unroll
            for (int r = 0; r < 4; r++) {
                int pr = lhi * 4 + r, pc = 16 * j + l15;
                lds_st1(myp, pr * 256 + SWZB(pr, pc * 2), f2bf(sc[j][r]));
            }
        fv4_t oacc[2] = {{0.f, 0.f, 0.f, 0.f}, {0.f, 0.f, 0.f, 0.f}};
        for (int kk = 0; kk < 4; kk++) {
            sv8_t pa = lds_ld8(myp, l15 * 256 + SWZB(l15, (kk * 32 + 8 * lhi) * 2));
            #pragma unroll
            for (int j = 0; j < 2; j++)
                oacc[j] = __builtin_amdgcn_mfma_f32_16x16x32_bf16(pa, vf[kk][j], oacc[j], 0, 0, 0);
        }
        #pragma unroll
        for (int r = 0; r < 4; r++) {
            int orow = rowt[r];
            float inv = 1.f / sm[r];
            #pragma unroll
            for (int j = 0; j < 2; j++) {
                int ocol = head * 32 + 16 * j + l15;
                float v = (orow < 98) ? oacc[j][r] * inv : 0.f;
                lds_st1(ot, orow * 256 + SWZB(orow, ocol * 2), f2bf(v));
            }
        }
    }
    __syncthreads();

    // proj: wave wv handles output cols wv*32..+31 over 112 rows, K=128
    {
        int nb = wv * 32;
        fv4_t acc[7][2];
        for (int m = 0; m < 7; m++) for (int j = 0; j < 2; j++) acc[m][j] = (fv4_t){0.f, 0.f, 0.f, 0.f};
        for (int kk = 0; kk < 4; kk++) {
            sv8_t b[2];
            #pragma unroll
            for (int j = 0; j < 2; j++)
                b[j] = *(const sv8_t*)(pwT + (size_t)(nb + 16 * j + l15) * 128 + kk * 32 + 8 * lhi);
            #pragma unroll
            for (int m = 0; m < 7; m++) {
                int ar = 16 * m + l15;
                sv8_t a = lds_ld8(ot, ar * 256 + SWZB(ar, (kk * 32 + 8 * lhi) * 2));
                #pragma unroll
                for (int j = 0; j < 2; j++)
                    acc[m][j] = __builtin_amdgcn_mfma_f32_16x16x32_bf16(a, b[j], acc[m][j], 0, 0, 0);
            }
        }
        int b_ = win >> 8;
        for (int m = 0; m < 7; m++)
            #pragma unroll
            for (int r = 0; r < 4; r++) {
                int row = 16 * m + lhi * 4 + r;
                if (row < 98) {
                    int it = row / 49, r2 = row - it * 49, ih = r2 / 7, iw = r2 - ih * 7;
                    int t = tw * 2 + it, h = hw * 7 + ih, w = ww * 7 + iw;
                    if (shifted) {
                        t += 1; if (t >= TT) t -= TT;
                        h += 3; if (h >= HH) h -= HH;
                        w += 3; if (w >= WW2) w -= WW2;
                    }
                    float* xp = xbuf + ((size_t)b_ * PSPAT + t * (HH * WW2) + h * WW2 + w) * 128 + nb;
                    #pragma unroll
                    for (int j = 0; j < 2; j++) {
                        int c = 16 * j + l15;
                        xp[c] += acc[m][j][r] + pb[nb + c];
                    }
                }
            }
    }
}

// ---------------- fused LN2 + fc1 + GELU + fc2 + residual ----------------
__global__ __launch_bounds__(256) void k_mlp(const float* __restrict__ xin,
                                             const float* __restrict__ g,
                                             const float* __restrict__ be,
                                             const unsigned short* __restrict__ w1T,  // [512][128]
                                             const float* __restrict__ b1p,
                                             const unsigned short* __restrict__ w2T,  // [128][512]
                                             const float* __restrict__ b2p,
                                             float* __restrict__ xbuf) {
    __shared__ unsigned short xt[64 * 128];
    __shared__ unsigned short ut[64 * 512];
    int tid = threadIdx.x;
    int row0 = blockIdx.x * 64;
    {
        int r = tid >> 2, q = tid & 3;
        const float* src = xin + (size_t)(row0 + r) * 128 + q * 32;
        float v[32];
        float s = 0.f, sq = 0.f;
        for (int i = 0; i < 8; i++) {
            f4ld_t f = *(const f4ld_t*)(src + i * 4);
            v[i * 4 + 0] = f.x; v[i * 4 + 1] = f.y; v[i * 4 + 2] = f.z; v[i * 4 + 3] = f.w;
            s += f.x + f.y + f.z + f.w;
            sq += f.x * f.x + f.y * f.y + f.z * f.z + f.w * f.w;
        }
        s += __shfl_xor(s, 1); sq += __shfl_xor(sq, 1);
        s += __shfl_xor(s, 2); sq += __shfl_xor(sq, 2);
        float mu = s * (1.f / 128.f);
        float var = sq * (1.f / 128.f) - mu * mu;
        float rs = rsqrtf(var + 1e-5f);
        for (int c0 = 0; c0 < 32; c0 += 8) {
            sv8_t o;
            #pragma unroll
            for (int i = 0; i < 8; i++) {
                int c = q * 32 + c0 + i;
                o[i] = (short)f2bf((v[c0 + i] - mu) * rs * g[c] + be[c]);
            }
            lds_st8(xt, r * 256 + SWZB(r, (q * 32 + c0) * 2), o);
        }
    }
    __syncthreads();
    int wv = tid >> 6, lane = tid & 63, l15 = lane & 15, lhi = lane >> 4;
    {   // fc1: wave cols wv*128 (8 frags)
        int nb = wv * 128;
        fv4_t acc[4][8];
        for (int m = 0; m < 4; m++) for (int j = 0; j < 8; j++) acc[m][j] = (fv4_t){0.f, 0.f, 0.f, 0.f};
        for (int kk = 0; kk < 4; kk++) {
            sv8_t a[4];
            #pragma unroll
            for (int m = 0; m < 4; m++) {
                int ar = 16 * m + l15;
                a[m] = lds_ld8(xt, ar * 256 + SWZB(ar, (kk * 32 + 8 * lhi) * 2));
            }
            #pragma unroll
            for (int j = 0; j < 8; j++) {
                sv8_t b = *(const sv8_t*)(w1T + (size_t)(nb + 16 * j + l15) * 128 + kk * 32 + 8 * lhi);
                #pragma unroll
                for (int m = 0; m < 4; m++)
                    acc[m][j] = __builtin_amdgcn_mfma_f32_16x16x32_bf16(a[m], b, acc[m][j], 0, 0, 0);
            }
        }
        for (int j = 0; j < 8; j++) {
            int col = nb + 16 * j + l15;
            float bb = b1p[col];
            #pragma unroll
            for (int m = 0; m < 4; m++)
                #pragma unroll
                for (int r = 0; r < 4; r++) {
                    float vv = acc[m][j][r] + bb;
                    float gl = vv * 0.5f * (1.f + erff(vv * 0.70710678118654752f));
                    int urow = 16 * m + lhi * 4 + r;
                    lds_st1(ut, urow * 1024 + SWZB(urow, col * 2), f2bf(gl));
                }
        }
    }
    __syncthreads();
    {   // fc2: wave cols wv*32 (2 frags), K=512
        int nb = wv * 32;
        fv4_t acc[4][2];
        for (int m = 0; m < 4; m++) for (int j = 0; j < 2; j++) acc[m][j] = (fv4_t){0.f, 0.f, 0.f, 0.f};
        for (int kk = 0; kk < 16; kk++) {
            sv8_t a[4];
            #pragma unroll
            for (int m = 0; m < 4; m++) {
                int ar = 16 * m + l15;
                a[m] = lds_ld8(ut, ar * 1024 + SWZB(ar, (kk * 32 + 8 * lhi) * 2));
            }
            #pragma unroll
            for (int j = 0; j < 2; j++) {
                sv8_t b = *(const sv8_t*)(w2T + (size_t)(nb + 16 * j + l15) * 512 + kk * 32 + 8 * lhi);
                #pragma unroll
                for (int m = 0; m < 4; m++)
                    acc[m][j] = __builtin_amdgcn_mfma_f32_16x16x32_bf16(a[m], b, acc[m][j], 0, 0, 0);
            }
        }
        #pragma unroll
        for (int m = 0; m < 4; m++)
            #pragma unroll
            for (int r = 0; r < 4; r++) {
                int row = row0 + 16 * m + lhi * 4 + r;
                float* xp = xbuf + (size_t)row * 128 + nb;
                #pragma unroll
                for (int j = 0; j < 2; j++) {
                    int c = 16 * j + l15;
                    xp[c] += acc[m][j][r] + b2p[nb + c];
                }
            }
    }
}

extern "C" void kernel_launch(void* const* d_in, const int* in_sizes, int n_in,
                              void* d_out, int out_size, void* d_ws, size_t ws_size,
                              hipStream_t stream) {
    const float* x_in   = (const float*)d_in[0];
    const float* ln1_g  = (const float*)d_in[1];
    const float* ln1_b  = (const float*)d_in[2];
    const float* qkv_w  = (const float*)d_in[3];
    const float* qkv_b  = (const float*)d_in[4];
    const float* rpb    = (const float*)d_in[5];
    const float* proj_w = (const float*)d_in[6];
    const float* proj_b = (const float*)d_in[7];
    const float* ln2_g  = (const float*)d_in[8];
    const float* ln2_b  = (const float*)d_in[9];
    const float* fc1_w  = (const float*)d_in[10];
    const float* fc1_b  = (const float*)d_in[11];
    const float* fc2_w  = (const float*)d_in[12];
    const float* fc2_b  = (const float*)d_in[13];
    float* out = (float*)d_out;

    char* ws = (char*)d_ws;
    float* xbuf = (float*)ws;                                       // 102,760,448 B
    unsigned short* qkvbuf = (unsigned short*)(ws + 102760448);     // 154,140,672 B
    unsigned short* wbase  = (unsigned short*)(ws + 102760448 + 154140672);
    float* biasb = (float*)(ws + 102760448 + 154140672 + 786432);   // 401,408 B

    k_transpose_in<<<dim3(PSPAT / 32, 4, BB), dim3(32, 8), 0, stream>>>(x_in, xbuf);

    for (int l = 0; l < 2; l++) {
        unsigned short* wqT = wbase + (size_t)l * 196608;
        unsigned short* wpT = wqT + 49152;
        unsigned short* w1T = wpT + 16384;
        unsigned short* w2T = w1T + 65536;
        k_prep_w<<<dim3(12, 4), dim3(32, 8), 0, stream>>>(qkv_w + (size_t)l * 49152, wqT, 128, 384);
        k_prep_w<<<dim3(4, 4),  dim3(32, 8), 0, stream>>>(proj_w + (size_t)l * 16384, wpT, 128, 128);
        k_prep_w<<<dim3(16, 4), dim3(32, 8), 0, stream>>>(fc1_w + (size_t)l * 65536, w1T, 128, 512);
        k_prep_w<<<dim3(4, 16), dim3(32, 8), 0, stream>>>(fc2_w + (size_t)l * 65536, w2T, 512, 128);
    }
    k_prep_bias<<<dim3(112, 4, 2), 112, 0, stream>>>(rpb, biasb);

    for (int layer = 0; layer < 2; layer++) {
        unsigned short* wqT = wbase + (size_t)layer * 196608;
        unsigned short* wpT = wqT + 49152;
        unsigned short* w1T = wpT + 16384;
        unsigned short* w2T = w1T + 65536;
        int shifted = layer & 1;

        k_qkv<<<TOK_TOTAL / 64, 256, 0, stream>>>(xbuf, ln1_g + layer * 128, ln1_b + layer * 128,
                                                  wqT, qkv_b + layer * 384, qkvbuf, shifted);
        k_attn_proj<<<BNW, 256, 0, stream>>>(qkvbuf, biasb + (size_t)layer * 4 * 112 * 112,
                                             wpT, proj_b + layer * 128, xbuf, shifted);
        k_mlp<<<TOK_TOTAL / 64, 256, 0, stream>>>(xbuf, ln2_g + layer * 128, ln2_b + layer * 128,
                                                  w1T, fc1_b + layer * 512, w2T, fc2_b + layer * 128, xbuf);
    }

    k_transpose_out<<<dim3(PSPAT / 32, 4, BB), dim3(32, 8), 0, stream>>>(xbuf, out);
}